// Round 10
// baseline (397.785 us; speedup 1.0000x reference)
//
#include <hip/hip_runtime.h>
#include <stdint.h>

typedef unsigned short u16;
typedef unsigned int u32;
typedef short bf16x8 __attribute__((ext_vector_type(8)));
typedef float f32x4 __attribute__((ext_vector_type(4)));
typedef u32 u32x2 __attribute__((ext_vector_type(2)));

#define GLOAD_LDS16(gptr, lptr)                                                \
  __builtin_amdgcn_global_load_lds(                                            \
      (__attribute__((address_space(1))) void*)(gptr),                         \
      (__attribute__((address_space(3))) void*)(lptr), 16, 0, 0)

#define WAITV4() asm volatile("s_waitcnt vmcnt(4)" ::: "memory")
#define WAITV0() asm volatile("s_waitcnt vmcnt(0)" ::: "memory")

#if __has_builtin(__builtin_amdgcn_exp2f)
#define EXP2F(x) __builtin_amdgcn_exp2f(x)
#else
#define EXP2F(x) exp2f(x)
#endif

__device__ __forceinline__ u16 f2bf(float f) {
  union { float f; uint32_t u; } v; v.f = f;
  return (u16)((v.u + 0x7fffu + ((v.u >> 16) & 1u)) >> 16);
}
__device__ __forceinline__ float bf2f(u16 h) {
  union { uint32_t u; float f; } v; v.u = ((uint32_t)h) << 16;
  return v.f;
}
__device__ __forceinline__ u32 cvt_pk_bf16(float lo, float hi) {
  u32 r;
  asm("v_cvt_pk_bf16_f32 %0, %1, %2" : "=v"(r) : "v"(lo), "v"(hi));
  return r;
}

// ---------------- convert x (f32 -> bf16), 8 elems/thread ----------------
__global__ void k_conv_bf16(const float* __restrict__ src, u16* __restrict__ dst, int n8) {
  int i = blockIdx.x * blockDim.x + threadIdx.x;
  if (i >= n8) return;
  const float4* s = (const float4*)src + (size_t)i * 2;
  float4 a = s[0], b = s[1];
  uint4 o;
  o.x = (uint32_t)f2bf(a.x) | ((uint32_t)f2bf(a.y) << 16);
  o.y = (uint32_t)f2bf(a.z) | ((uint32_t)f2bf(a.w) << 16);
  o.z = (uint32_t)f2bf(b.x) | ((uint32_t)f2bf(b.y) << 16);
  o.w = (uint32_t)f2bf(b.z) | ((uint32_t)f2bf(b.w) << 16);
  ((uint4*)dst)[i] = o;
}

// ---------------- transpose f32 [R][C] -> bf16 [C][R] ----------------
__global__ void k_transpose_bf16(const float* __restrict__ src, u16* __restrict__ dst,
                                 int R, int C) {
  __shared__ float tile[32][33];
  int cb = blockIdx.x * 32, rb = blockIdx.y * 32;
  int tx = threadIdx.x, ty = threadIdx.y;
#pragma unroll
  for (int j = 0; j < 4; ++j)
    tile[ty + j * 8][tx] = src[(size_t)(rb + ty + j * 8) * C + cb + tx];
  __syncthreads();
#pragma unroll
  for (int j = 0; j < 4; ++j)
    dst[(size_t)(cb + ty + j * 8) * R + rb + tx] = f2bf(tile[tx][ty + j * 8]);
}

// ---------------- transpose V slice of cqkv -> VT[b*8+kvh][64][2048] (bf16) ----
__global__ void k_transpose_v(const u16* __restrict__ cqkv, u16* __restrict__ vt) {
  __shared__ u16 tile[32][34];
  int st = blockIdx.x, dt = blockIdx.y, bk = blockIdx.z;
  int b = bk >> 3, kvh = bk & 7;
  int tx = threadIdx.x, ty = threadIdx.y;
  const u16* src = cqkv + (size_t)(b * 2048 + st * 32) * 3072 + 2560 + kvh * 64 + dt * 32;
#pragma unroll
  for (int j = 0; j < 4; ++j)
    tile[ty + j * 8][tx] = src[(size_t)(ty + j * 8) * 3072 + tx];
  __syncthreads();
  u16* dst = vt + ((size_t)(bk * 64 + dt * 32)) * 2048 + st * 32;
#pragma unroll
  for (int j = 0; j < 4; ++j)
    dst[(size_t)(ty + j * 8) * 2048 + tx] = tile[tx][ty + j * 8];
}

// ---------------- GEMM v3: 3-buffer counted-vmcnt pipeline, XCD-swizzled ------
// (r9-proven; unchanged)
template <bool BF16OUT>
__global__ __launch_bounds__(256) void k_gemm_bt(
    const u16* __restrict__ A, const u16* __restrict__ Bt,
    const float* __restrict__ bias, void* __restrict__ Cptr,
    int M, int N, int K, int gx, int nwg) {
  __shared__ u16 As[3][128 * 32];
  __shared__ u16 Bs[3][128 * 32];
  const int t = threadIdx.x;
  const int lane = t & 63;
  const int w = t >> 6, wr = w >> 1, wc = w & 1;
  const int bid = blockIdx.x;
  const int cpx = nwg >> 3;
  const int swz = (bid & 7) * cpx + (bid >> 3);
  const int brow = (swz / gx) * 128, bcol = (swz % gx) * 128;
  const int g = lane >> 4, q = lane & 15;

  f32x4 acc[4][4] = {};
  const int srow = t >> 2;
  const int sj = t & 3;
  const int jx = sj ^ ((srow >> 1) & 3);
  const int nkt = K >> 5;

  const u16* gA = A + (size_t)(brow + srow) * K + jx * 8;
  const u16* gB = Bt + (size_t)(bcol + srow) * K + jx * 8;

  auto stage = [&](int bb) {
    GLOAD_LDS16(gA,                  (char*)(&As[bb][0]) + t * 16);
    GLOAD_LDS16(gA + (size_t)64 * K, (char*)(&As[bb][0]) + 4096 + t * 16);
    GLOAD_LDS16(gB,                  (char*)(&Bs[bb][0]) + t * 16);
    GLOAD_LDS16(gB + (size_t)64 * K, (char*)(&Bs[bb][0]) + 4096 + t * 16);
    gA += 32; gB += 32;
  };

  stage(0);
  stage(1);
  WAITV4();
  __builtin_amdgcn_s_barrier();
  __builtin_amdgcn_sched_barrier(0);

  int cur = 0;
  for (int kt = 0; kt < nkt; ++kt) {
    const u16* Ac = As[cur];
    const u16* Bc = Bs[cur];
    bf16x8 a[4], b[4];
#pragma unroll
    for (int mt = 0; mt < 4; ++mt) {
      int row = wr * 64 + mt * 16 + q;
      int pos = g ^ ((row >> 1) & 3);
      a[mt] = *(const bf16x8*)(Ac + row * 32 + pos * 8);
    }
#pragma unroll
    for (int nt = 0; nt < 4; ++nt) {
      int row = wc * 64 + nt * 16 + q;
      int pos = g ^ ((row >> 1) & 3);
      b[nt] = *(const bf16x8*)(Bc + row * 32 + pos * 8);
    }
    if (kt + 2 < nkt) {
      int b2 = cur + 2; if (b2 >= 3) b2 -= 3;
      stage(b2);
    }
    __builtin_amdgcn_s_setprio(1);
#pragma unroll
    for (int mt = 0; mt < 4; ++mt)
#pragma unroll
      for (int nt = 0; nt < 4; ++nt)
        acc[mt][nt] = __builtin_amdgcn_mfma_f32_16x16x32_bf16(a[mt], b[nt], acc[mt][nt], 0, 0, 0);
    __builtin_amdgcn_s_setprio(0);
    if (kt + 1 < nkt) {
      if (kt + 2 < nkt) WAITV4(); else WAITV0();
      __builtin_amdgcn_s_barrier();
      __builtin_amdgcn_sched_barrier(0);
    }
    ++cur; if (cur >= 3) cur -= 3;
  }
#pragma unroll
  for (int nt = 0; nt < 4; ++nt) {
    int col = bcol + wc * 64 + nt * 16 + q;
    float bv_ = bias[col];
#pragma unroll
    for (int mt = 0; mt < 4; ++mt) {
#pragma unroll
      for (int r = 0; r < 4; ++r) {
        int row = brow + wr * 64 + mt * 16 + g * 4 + r;
        float val = acc[mt][nt][r] + bv_;
        if (BF16OUT)
          ((u16*)Cptr)[(size_t)row * N + col] = f2bf(val);
        else
          ((float*)Cptr)[(size_t)row * N + col] = val;
      }
    }
  }
}

// ---------------- flash attention v9: K-only LDS, V direct from global -------
// Block = 4 waves, 128 q rows (2 subs). LDS 25600B -> high occupancy (grid 1024).
// r8 inner structure (plain __syncthreads, 2-buffer K).
#define LOG2E 1.44269504088896340736f
__global__ __launch_bounds__(256) void k_attn(const u16* __restrict__ qkv,
                                              const u16* __restrict__ vt,
                                              u16* __restrict__ out) {
  const int qt = blockIdx.x, h = blockIdx.y, b = blockIdx.z;
  const int kvh = h >> 2;
  const int t = threadIdx.x, lane = t & 63, w = t >> 6;
  const int g = lane >> 4, q16 = lane & 15;
  const int LDQ = 3072;

  __shared__ u16 Ksh[2][64 * 64];   // [kv][d], chunk (row,j) holds dc = j ^ (row&7)
  __shared__ u16 Psh[4][16 * 72] __attribute__((aligned(16)));

  // Q fragments, scaled by 1/8 (exact in bf16)
  bf16x8 qf[2][2];
#pragma unroll
  for (int s = 0; s < 2; ++s) {
    const size_t qrow = (size_t)(b * 2048 + qt * 128 + s * 64 + w * 16 + q16);
#pragma unroll
    for (int c = 0; c < 2; ++c) {
      bf16x8 tmp = *(const bf16x8*)(qkv + qrow * LDQ + h * 64 + c * 32 + g * 8);
#pragma unroll
      for (int i = 0; i < 8; ++i)
        tmp[i] = (short)f2bf(bf2f((u16)tmp[i]) * 0.125f);
      qf[s][c] = tmp;
    }
  }

  f32x4 acc[2][4] = {};
  float m_run[2], l_run[2];
  m_run[0] = m_run[1] = -__builtin_inff();
  l_run[0] = l_run[1] = 0.f;

  const int kbase = b * 2048;
  const int koff = 2048 + kvh * 64;
  const u16* vtb = vt + (size_t)((b * 8 + kvh) * 64) * 2048;
  const int srow = t >> 3;  // 0..31
  const int sj = t & 7;
  const int cx = sj ^ (srow & 7);

  const u16* gk = qkv + (size_t)(kbase + srow) * LDQ + koff + cx * 8;
  // per-dt V row pointers (row d = dt*16 + q16, col base g*8), advance 64/tile
  const u16* gvd0 = vtb + (size_t)(0 * 16 + q16) * 2048 + g * 8;
  const u16* gvd1 = vtb + (size_t)(1 * 16 + q16) * 2048 + g * 8;
  const u16* gvd2 = vtb + (size_t)(2 * 16 + q16) * 2048 + g * 8;
  const u16* gvd3 = vtb + (size_t)(3 * 16 + q16) * 2048 + g * 8;

  auto stage = [&](int bb) {
    GLOAD_LDS16(gk,            (char*)(&Ksh[bb][0]) + t * 16);
    GLOAD_LDS16(gk + 32 * LDQ, (char*)(&Ksh[bb][0]) + 4096 + t * 16);
    gk += 64 * LDQ;
  };

  stage(0);
  __syncthreads();
  int cur = 0;

  for (int kt = 0; kt < 32; ++kt) {
    if (kt < 31) stage(cur ^ 1);   // prefetch next K tile
    const u16* Kc = Ksh[cur];
    // V fragments direct from global (softmax-independent; compiler hoists early)
    bf16x8 vf[2][4];
#pragma unroll
    for (int c = 0; c < 2; ++c) {
      vf[c][0] = *(const bf16x8*)(gvd0 + c * 32);
      vf[c][1] = *(const bf16x8*)(gvd1 + c * 32);
      vf[c][2] = *(const bf16x8*)(gvd2 + c * 32);
      vf[c][3] = *(const bf16x8*)(gvd3 + c * 32);
    }
    gvd0 += 64; gvd1 += 64; gvd2 += 64; gvd3 += 64;

    // ---- QK^T swapped: sc = mfma(K, Q) -> row = kv (nt*16+g*4+r), col = q16
    f32x4 sc[2][4] = {};
    __builtin_amdgcn_s_setprio(1);
#pragma unroll
    for (int c = 0; c < 2; ++c) {
#pragma unroll
      for (int nt = 0; nt < 4; ++nt) {
        int row = nt * 16 + q16;
        bf16x8 kf = *(const bf16x8*)(Kc + row * 64 + (((c * 4 + g) ^ (row & 7)) << 3));
        sc[0][nt] = __builtin_amdgcn_mfma_f32_16x16x32_bf16(kf, qf[0][c], sc[0][nt], 0, 0, 0);
        sc[1][nt] = __builtin_amdgcn_mfma_f32_16x16x32_bf16(kf, qf[1][c], sc[1][nt], 0, 0, 0);
      }
    }
    __builtin_amdgcn_s_setprio(0);

    bf16x8 pf[2][2];
#pragma unroll
    for (int s = 0; s < 2; ++s) {
      float mt_ = sc[s][0][0];
#pragma unroll
      for (int nt = 0; nt < 4; ++nt)
#pragma unroll
        for (int r = 0; r < 4; ++r)
          mt_ = fmaxf(mt_, sc[s][nt][r]);
      mt_ = fmaxf(mt_, __shfl_xor(mt_, 16, 64));
      mt_ = fmaxf(mt_, __shfl_xor(mt_, 32, 64));
      if (__any(mt_ > m_run[s])) {
        float mn = fmaxf(m_run[s], mt_);
        float alpha = EXP2F((m_run[s] - mn) * LOG2E);
        m_run[s] = mn;
        l_run[s] *= alpha;
#pragma unroll
        for (int r = 0; r < 4; ++r) {
          float ar = __shfl(alpha, g * 4 + r, 64);
#pragma unroll
          for (int dt = 0; dt < 4; ++dt) acc[s][dt][r] *= ar;
        }
      }
      float mL = m_run[s] * LOG2E;
      float lt = 0.f;
#pragma unroll
      for (int nt = 0; nt < 4; ++nt)
#pragma unroll
        for (int r = 0; r < 4; ++r) {
          float p_ = EXP2F(fmaf(sc[s][nt][r], LOG2E, -mL));
          sc[s][nt][r] = p_;
          lt += p_;
        }
      lt += __shfl_xor(lt, 16, 64);
      lt += __shfl_xor(lt, 32, 64);
      l_run[s] += lt;
      u16* prow = &Psh[w][q16 * 72];
#pragma unroll
      for (int nt = 0; nt < 4; ++nt) {
        u32x2 pk;
        pk.x = cvt_pk_bf16(sc[s][nt][0], sc[s][nt][1]);
        pk.y = cvt_pk_bf16(sc[s][nt][2], sc[s][nt][3]);
        *(u32x2*)(prow + nt * 16 + g * 4) = pk;
      }
      pf[s][0] = *(const bf16x8*)(&Psh[w][q16 * 72 + g * 8]);
      pf[s][1] = *(const bf16x8*)(&Psh[w][q16 * 72 + 32 + g * 8]);
    }

    // ---- PV: vf already in registers ----
    __builtin_amdgcn_s_setprio(1);
#pragma unroll
    for (int c = 0; c < 2; ++c) {
#pragma unroll
      for (int dt = 0; dt < 4; ++dt) {
        acc[0][dt] = __builtin_amdgcn_mfma_f32_16x16x32_bf16(pf[0][c], vf[c][dt], acc[0][dt], 0, 0, 0);
        acc[1][dt] = __builtin_amdgcn_mfma_f32_16x16x32_bf16(pf[1][c], vf[c][dt], acc[1][dt], 0, 0, 0);
      }
    }
    __builtin_amdgcn_s_setprio(0);

    __syncthreads();   // drains prefetch + syncs K buffer swap
    cur ^= 1;
  }

  // ---- epilogue: rows g*4+r, cols dt*16+q16 ----
#pragma unroll
  for (int s = 0; s < 2; ++s)
#pragma unroll
    for (int r = 0; r < 4; ++r) {
      float linv = 1.0f / __shfl(l_run[s], g * 4 + r, 64);
      size_t orow = (size_t)(b * 2048 + qt * 128 + s * 64 + w * 16 + g * 4 + r);
#pragma unroll
      for (int dt = 0; dt < 4; ++dt)
        out[orow * 2048 + h * 64 + dt * 16 + q16] = f2bf(acc[s][dt][r] * linv);
    }
}

// ---------------- launch ----------------
extern "C" void kernel_launch(void* const* d_in, const int* in_sizes, int n_in,
                              void* d_out, int out_size, void* d_ws, size_t ws_size,
                              hipStream_t stream) {
  const float* x  = (const float*)d_in[0];
  const float* Wq = (const float*)d_in[1];
  const float* bq = (const float*)d_in[2];
  const float* Wk = (const float*)d_in[3];
  const float* bk = (const float*)d_in[4];
  const float* Wv = (const float*)d_in[5];
  const float* bv = (const float*)d_in[6];
  const float* Wo = (const float*)d_in[7];
  const float* bo = (const float*)d_in[8];
  float* out = (float*)d_out;

  char* ws = (char*)d_ws;
  u16*   xb    = (u16*)(ws + 0);               // 4096x2048 bf16 = 16 MB; reused as VT after QKV GEMM
  u16*   wqkvT = (u16*)(ws + 16777216);        // 3072x2048 bf16 = 12 MB
  u16*   woT   = (u16*)(ws + 29360128);        // 2048x2048 bf16 = 8 MB
  float* bqkv  = (float*)(ws + 37748736);      // 3072 f32
  u16*   cqkv  = (u16*)(ws + 37761024);        // 4096x3072 bf16 = 24 MB
  u16*   aout  = (u16*)(ws + 62926848);        // 4096x2048 bf16 = 16 MB
  u16*   vtb   = xb;                           // VT: 16x64x2048 bf16 = 4 MB (xb dead post-GEMM)
  (void)ws_size; (void)in_sizes; (void)n_in; (void)out_size;

  hipMemcpyAsync(bqkv, bq, 2048 * sizeof(float), hipMemcpyDeviceToDevice, stream);
  hipMemcpyAsync(bqkv + 2048, bk, 512 * sizeof(float), hipMemcpyDeviceToDevice, stream);
  hipMemcpyAsync(bqkv + 2560, bv, 512 * sizeof(float), hipMemcpyDeviceToDevice, stream);

  k_conv_bf16<<<4096, 256, 0, stream>>>(x, xb, 1048576);
  dim3 tb(32, 8);
  k_transpose_bf16<<<dim3(64, 64), tb, 0, stream>>>(Wq, wqkvT, 2048, 2048);
  k_transpose_bf16<<<dim3(16, 64), tb, 0, stream>>>(Wk, wqkvT + 2048 * 2048, 2048, 512);
  k_transpose_bf16<<<dim3(16, 64), tb, 0, stream>>>(Wv, wqkvT + 2560 * 2048, 2048, 512);
  k_transpose_bf16<<<dim3(64, 64), tb, 0, stream>>>(Wo, woT, 2048, 2048);

  k_gemm_bt<true><<<768, 256, 0, stream>>>(xb, wqkvT, bqkv, cqkv, 4096, 3072, 2048, 24, 768);
  k_transpose_v<<<dim3(64, 2, 16), tb, 0, stream>>>(cqkv, vtb);
  k_attn<<<dim3(16, 32, 2), 256, 0, stream>>>(cqkv, vtb, aout);
  k_gemm_bt<false><<<512, 256, 0, stream>>>(aout, woT, bo, out, 4096, 2048, 2048, 16, 512);
}

// Round 11
// 374.303 us; speedup vs baseline: 1.0627x; 1.0627x over previous
//
#include <hip/hip_runtime.h>
#include <stdint.h>

typedef unsigned short u16;
typedef unsigned int u32;
typedef short bf16x8 __attribute__((ext_vector_type(8)));
typedef float f32x4 __attribute__((ext_vector_type(4)));
typedef u32 u32x2 __attribute__((ext_vector_type(2)));

#define GLOAD_LDS16(gptr, lptr)                                                \
  __builtin_amdgcn_global_load_lds(                                            \
      (__attribute__((address_space(1))) void*)(gptr),                         \
      (__attribute__((address_space(3))) void*)(lptr), 16, 0, 0)

#define WAITV4() asm volatile("s_waitcnt vmcnt(4)" ::: "memory")
#define WAITV0() asm volatile("s_waitcnt vmcnt(0)" ::: "memory")

#if __has_builtin(__builtin_amdgcn_exp2f)
#define EXP2F(x) __builtin_amdgcn_exp2f(x)
#else
#define EXP2F(x) exp2f(x)
#endif

__device__ __forceinline__ u16 f2bf(float f) {
  union { float f; uint32_t u; } v; v.f = f;
  return (u16)((v.u + 0x7fffu + ((v.u >> 16) & 1u)) >> 16);
}
__device__ __forceinline__ float bf2f(u16 h) {
  union { uint32_t u; float f; } v; v.u = ((uint32_t)h) << 16;
  return v.f;
}
__device__ __forceinline__ u32 cvt_pk_bf16(float lo, float hi) {
  u32 r;
  asm("v_cvt_pk_bf16_f32 %0, %1, %2" : "=v"(r) : "v"(lo), "v"(hi));
  return r;
}

// ---------------- convert x (f32 -> bf16), 8 elems/thread ----------------
__global__ void k_conv_bf16(const float* __restrict__ src, u16* __restrict__ dst, int n8) {
  int i = blockIdx.x * blockDim.x + threadIdx.x;
  if (i >= n8) return;
  const float4* s = (const float4*)src + (size_t)i * 2;
  float4 a = s[0], b = s[1];
  uint4 o;
  o.x = (uint32_t)f2bf(a.x) | ((uint32_t)f2bf(a.y) << 16);
  o.y = (uint32_t)f2bf(a.z) | ((uint32_t)f2bf(a.w) << 16);
  o.z = (uint32_t)f2bf(b.x) | ((uint32_t)f2bf(b.y) << 16);
  o.w = (uint32_t)f2bf(b.z) | ((uint32_t)f2bf(b.w) << 16);
  ((uint4*)dst)[i] = o;
}

// ---------------- transpose f32 [R][C] -> bf16 [C][R] ----------------
__global__ void k_transpose_bf16(const float* __restrict__ src, u16* __restrict__ dst,
                                 int R, int C) {
  __shared__ float tile[32][33];
  int cb = blockIdx.x * 32, rb = blockIdx.y * 32;
  int tx = threadIdx.x, ty = threadIdx.y;
#pragma unroll
  for (int j = 0; j < 4; ++j)
    tile[ty + j * 8][tx] = src[(size_t)(rb + ty + j * 8) * C + cb + tx];
  __syncthreads();
#pragma unroll
  for (int j = 0; j < 4; ++j)
    dst[(size_t)(cb + ty + j * 8) * R + rb + tx] = f2bf(tile[tx][ty + j * 8]);
}

// ---------------- transpose V slice of cqkv -> VT[b*8+kvh][64][2048] (bf16) ----
__global__ void k_transpose_v(const u16* __restrict__ cqkv, u16* __restrict__ vt) {
  __shared__ u16 tile[32][34];
  int st = blockIdx.x, dt = blockIdx.y, bk = blockIdx.z;
  int b = bk >> 3, kvh = bk & 7;
  int tx = threadIdx.x, ty = threadIdx.y;
  const u16* src = cqkv + (size_t)(b * 2048 + st * 32) * 3072 + 2560 + kvh * 64 + dt * 32;
#pragma unroll
  for (int j = 0; j < 4; ++j)
    tile[ty + j * 8][tx] = src[(size_t)(ty + j * 8) * 3072 + tx];
  __syncthreads();
  u16* dst = vt + ((size_t)(bk * 64 + dt * 32)) * 2048 + st * 32;
#pragma unroll
  for (int j = 0; j < 4; ++j)
    dst[(size_t)(ty + j * 8) * 2048 + tx] = tile[tx][ty + j * 8];
}

// ---------------- GEMM v4: 256x256 tile, 8 waves, 3-buffer counted-vmcnt ------
// Same sync skeleton as proven v3 (4 loads/stage, WAITV4/WAITV0, s_barrier),
// scaled to 256^2: 32 MFMA : 12 ds_read_b128 per K-step per wave (MFMA-bound).
template <bool BF16OUT>
__global__ __launch_bounds__(512) void k_gemm_bt(
    const u16* __restrict__ A, const u16* __restrict__ Bt,
    const float* __restrict__ bias, void* __restrict__ Cptr,
    int M, int N, int K, int gx, int nwg) {
  __shared__ u16 As[3][256 * 32];
  __shared__ u16 Bs[3][256 * 32];
  const int t = threadIdx.x;
  const int lane = t & 63;
  const int w = t >> 6;                 // 0..7
  const int wr = w >> 2, wc = w & 3;    // 2M x 4N wave grid; wave tile 128x64
  const int bid = blockIdx.x;
  const int cpx = nwg >> 3;
  const int swz = (bid & 7) * cpx + (bid >> 3);
  const int brow = (swz / gx) * 256, bcol = (swz % gx) * 256;
  const int g = lane >> 4, q = lane & 15;

  f32x4 acc[8][4] = {};
  const int srow = t >> 2;              // 0..127
  const int sj = t & 3;
  const int jx = sj ^ ((srow >> 1) & 3);  // same for srow and srow+128
  const int nkt = K >> 5;

  const u16* gA = A + (size_t)(brow + srow) * K + jx * 8;
  const u16* gB = Bt + (size_t)(bcol + srow) * K + jx * 8;

  auto stage = [&](int bb) {
    GLOAD_LDS16(gA,                   (char*)(&As[bb][0]) + t * 16);
    GLOAD_LDS16(gA + (size_t)128 * K, (char*)(&As[bb][0]) + 8192 + t * 16);
    GLOAD_LDS16(gB,                   (char*)(&Bs[bb][0]) + t * 16);
    GLOAD_LDS16(gB + (size_t)128 * K, (char*)(&Bs[bb][0]) + 8192 + t * 16);
    gA += 32; gB += 32;
  };

  stage(0);
  stage(1);
  WAITV4();                     // buffer 0 landed; buffer 1 still in flight
  __builtin_amdgcn_s_barrier();
  __builtin_amdgcn_sched_barrier(0);

  int cur = 0;
  for (int kt = 0; kt < nkt; ++kt) {
    const u16* Ac = As[cur];
    const u16* Bc = Bs[cur];
    bf16x8 a[8], b[4];
#pragma unroll
    for (int mt = 0; mt < 8; ++mt) {
      int row = wr * 128 + mt * 16 + q;
      int pos = g ^ ((row >> 1) & 3);
      a[mt] = *(const bf16x8*)(Ac + row * 32 + pos * 8);
    }
#pragma unroll
    for (int nt = 0; nt < 4; ++nt) {
      int row = wc * 64 + nt * 16 + q;
      int pos = g ^ ((row >> 1) & 3);
      b[nt] = *(const bf16x8*)(Bc + row * 32 + pos * 8);
    }
    if (kt + 2 < nkt) {
      int b2 = cur + 2; if (b2 >= 3) b2 -= 3;
      stage(b2);
    }
    __builtin_amdgcn_s_setprio(1);
#pragma unroll
    for (int mt = 0; mt < 8; ++mt)
#pragma unroll
      for (int nt = 0; nt < 4; ++nt)
        acc[mt][nt] = __builtin_amdgcn_mfma_f32_16x16x32_bf16(a[mt], b[nt], acc[mt][nt], 0, 0, 0);
    __builtin_amdgcn_s_setprio(0);
    if (kt + 1 < nkt) {
      if (kt + 2 < nkt) WAITV4(); else WAITV0();
      __builtin_amdgcn_s_barrier();
      __builtin_amdgcn_sched_barrier(0);
    }
    ++cur; if (cur >= 3) cur -= 3;
  }
#pragma unroll
  for (int nt = 0; nt < 4; ++nt) {
    int col = bcol + wc * 64 + nt * 16 + q;
    float bv_ = bias[col];
#pragma unroll
    for (int mt = 0; mt < 8; ++mt) {
#pragma unroll
      for (int r = 0; r < 4; ++r) {
        int row = brow + wr * 128 + mt * 16 + g * 4 + r;
        float val = acc[mt][nt][r] + bv_;
        if (BF16OUT)
          ((u16*)Cptr)[(size_t)row * N + col] = f2bf(val);
        else
          ((float*)Cptr)[(size_t)row * N + col] = val;
      }
    }
  }
}

// ---------------- flash attention (r8-proven exact): 4 q-subtiles, 2-buffer ----
// Block = 4 waves. Wave w, sub s -> q rows qt*256 + s*64 + w*16 + 0..15.
#define LOG2E 1.44269504088896340736f
__global__ __launch_bounds__(256) void k_attn(const u16* __restrict__ qkv,
                                              const u16* __restrict__ vt,
                                              u16* __restrict__ out) {
  const int qt = blockIdx.x, h = blockIdx.y, b = blockIdx.z;
  const int kvh = h >> 2;
  const int t = threadIdx.x, lane = t & 63, w = t >> 6;
  const int g = lane >> 4, q16 = lane & 15;
  const int LDQ = 3072;

  __shared__ u16 Ksh[2][64 * 64];   // [kv][d], chunk (row,j) holds dc = j ^ (row&7)
  __shared__ u16 Vsh[2][64 * 64];   // [d][kv], chunk (d,j)  holds kc = j ^ (d&7)
  __shared__ u16 Psh[4][16 * 72] __attribute__((aligned(16)));

  // Q fragments, scaled by 1/8 (exact in bf16)
  bf16x8 qf[4][2];
#pragma unroll
  for (int s = 0; s < 4; ++s) {
    const size_t qrow = (size_t)(b * 2048 + qt * 256 + s * 64 + w * 16 + q16);
#pragma unroll
    for (int c = 0; c < 2; ++c) {
      bf16x8 tmp = *(const bf16x8*)(qkv + qrow * LDQ + h * 64 + c * 32 + g * 8);
#pragma unroll
      for (int i = 0; i < 8; ++i)
        tmp[i] = (short)f2bf(bf2f((u16)tmp[i]) * 0.125f);
      qf[s][c] = tmp;
    }
  }

  f32x4 acc[4][4] = {};
  float m_run[4], l_run[4];
#pragma unroll
  for (int s = 0; s < 4; ++s) { m_run[s] = -__builtin_inff(); l_run[s] = 0.f; }

  const int kbase = b * 2048;
  const int koff = 2048 + kvh * 64;
  const u16* vtb = vt + (size_t)((b * 8 + kvh) * 64) * 2048;
  const int srow = t >> 3;  // 0..31
  const int sj = t & 7;
  const int cx = sj ^ (srow & 7);

  const u16* gk = qkv + (size_t)(kbase + srow) * LDQ + koff + cx * 8;
  const u16* gv = vtb + (size_t)srow * 2048 + cx * 8;

  auto stage = [&](int bb) {
    GLOAD_LDS16(gk,               (char*)(&Ksh[bb][0]) + t * 16);
    GLOAD_LDS16(gk + 32 * LDQ,    (char*)(&Ksh[bb][0]) + 4096 + t * 16);
    GLOAD_LDS16(gv,               (char*)(&Vsh[bb][0]) + t * 16);
    GLOAD_LDS16(gv + 32 * 2048,   (char*)(&Vsh[bb][0]) + 4096 + t * 16);
    gk += 64 * LDQ; gv += 64;
  };

  stage(0);
  __syncthreads();
  int cur = 0;

  for (int kt = 0; kt < 32; ++kt) {
    if (kt < 31) stage(cur ^ 1);
    const u16* Kc = Ksh[cur];
    const u16* Vc = Vsh[cur];

#pragma unroll
    for (int p2 = 0; p2 < 2; ++p2) {
      const int s0 = p2 * 2, s1 = p2 * 2 + 1;
      // ---- QK^T swapped: sc = mfma(K, Q) -> row = kv (nt*16+g*4+r), col = q16
      f32x4 sc[2][4] = {};
      __builtin_amdgcn_s_setprio(1);
#pragma unroll
      for (int c = 0; c < 2; ++c) {
#pragma unroll
        for (int nt = 0; nt < 4; ++nt) {
          int row = nt * 16 + q16;
          bf16x8 kf = *(const bf16x8*)(Kc + row * 64 + (((c * 4 + g) ^ (row & 7)) << 3));
          sc[0][nt] = __builtin_amdgcn_mfma_f32_16x16x32_bf16(kf, qf[s0][c], sc[0][nt], 0, 0, 0);
          sc[1][nt] = __builtin_amdgcn_mfma_f32_16x16x32_bf16(kf, qf[s1][c], sc[1][nt], 0, 0, 0);
        }
      }
      __builtin_amdgcn_s_setprio(0);

      bf16x8 pf[2][2];
#pragma unroll
      for (int i2 = 0; i2 < 2; ++i2) {
        const int s = p2 * 2 + i2;
        float mt_ = sc[i2][0][0];
#pragma unroll
        for (int nt = 0; nt < 4; ++nt)
#pragma unroll
          for (int r = 0; r < 4; ++r)
            mt_ = fmaxf(mt_, sc[i2][nt][r]);
        mt_ = fmaxf(mt_, __shfl_xor(mt_, 16, 64));
        mt_ = fmaxf(mt_, __shfl_xor(mt_, 32, 64));
        if (__any(mt_ > m_run[s])) {
          float mn = fmaxf(m_run[s], mt_);
          float alpha = EXP2F((m_run[s] - mn) * LOG2E);
          m_run[s] = mn;
          l_run[s] *= alpha;
#pragma unroll
          for (int r = 0; r < 4; ++r) {
            float ar = __shfl(alpha, g * 4 + r, 64);
#pragma unroll
            for (int dt = 0; dt < 4; ++dt) acc[s][dt][r] *= ar;
          }
        }
        float mL = m_run[s] * LOG2E;
        float lt = 0.f;
#pragma unroll
        for (int nt = 0; nt < 4; ++nt)
#pragma unroll
          for (int r = 0; r < 4; ++r) {
            float p_ = EXP2F(fmaf(sc[i2][nt][r], LOG2E, -mL));
            sc[i2][nt][r] = p_;
            lt += p_;
          }
        lt += __shfl_xor(lt, 16, 64);
        lt += __shfl_xor(lt, 32, 64);
        l_run[s] += lt;
        u16* prow = &Psh[w][q16 * 72];
#pragma unroll
        for (int nt = 0; nt < 4; ++nt) {
          u32x2 pk;
          pk.x = cvt_pk_bf16(sc[i2][nt][0], sc[i2][nt][1]);
          pk.y = cvt_pk_bf16(sc[i2][nt][2], sc[i2][nt][3]);
          *(u32x2*)(prow + nt * 16 + g * 4) = pk;
        }
        pf[i2][0] = *(const bf16x8*)(&Psh[w][q16 * 72 + g * 8]);
        pf[i2][1] = *(const bf16x8*)(&Psh[w][q16 * 72 + 32 + g * 8]);
      }

      // ---- PV pair ----
      __builtin_amdgcn_s_setprio(1);
#pragma unroll
      for (int c = 0; c < 2; ++c) {
        int kc = c * 4 + g;
#pragma unroll
        for (int dt = 0; dt < 4; ++dt) {
          int d = dt * 16 + q16;
          bf16x8 vf = *(const bf16x8*)(Vc + d * 64 + ((kc ^ (d & 7)) << 3));
          acc[s0][dt] = __builtin_amdgcn_mfma_f32_16x16x32_bf16(pf[0][c], vf, acc[s0][dt], 0, 0, 0);
          acc[s1][dt] = __builtin_amdgcn_mfma_f32_16x16x32_bf16(pf[1][c], vf, acc[s1][dt], 0, 0, 0);
        }
      }
      __builtin_amdgcn_s_setprio(0);
    }

    __syncthreads();
    cur ^= 1;
  }

  // ---- epilogue: rows g*4+r, cols dt*16+q16 ----
#pragma unroll
  for (int s = 0; s < 4; ++s)
#pragma unroll
    for (int r = 0; r < 4; ++r) {
      float linv = 1.0f / __shfl(l_run[s], g * 4 + r, 64);
      size_t orow = (size_t)(b * 2048 + qt * 256 + s * 64 + w * 16 + g * 4 + r);
#pragma unroll
      for (int dt = 0; dt < 4; ++dt)
        out[orow * 2048 + h * 64 + dt * 16 + q16] = f2bf(acc[s][dt][r] * linv);
    }
}

// ---------------- launch ----------------
extern "C" void kernel_launch(void* const* d_in, const int* in_sizes, int n_in,
                              void* d_out, int out_size, void* d_ws, size_t ws_size,
                              hipStream_t stream) {
  const float* x  = (const float*)d_in[0];
  const float* Wq = (const float*)d_in[1];
  const float* bq = (const float*)d_in[2];
  const float* Wk = (const float*)d_in[3];
  const float* bk = (const float*)d_in[4];
  const float* Wv = (const float*)d_in[5];
  const float* bv = (const float*)d_in[6];
  const float* Wo = (const float*)d_in[7];
  const float* bo = (const float*)d_in[8];
  float* out = (float*)d_out;

  char* ws = (char*)d_ws;
  u16*   xb    = (u16*)(ws + 0);               // 4096x2048 bf16 = 16 MB; reused as VT after QKV GEMM
  u16*   wqkvT = (u16*)(ws + 16777216);        // 3072x2048 bf16 = 12 MB
  u16*   woT   = (u16*)(ws + 29360128);        // 2048x2048 bf16 = 8 MB
  float* bqkv  = (float*)(ws + 37748736);      // 3072 f32
  u16*   cqkv  = (u16*)(ws + 37761024);        // 4096x3072 bf16 = 24 MB
  u16*   aout  = (u16*)(ws + 62926848);        // 4096x2048 bf16 = 16 MB
  u16*   vtb   = xb;                           // VT: 16x64x2048 bf16 = 4 MB (xb dead post-GEMM)
  (void)ws_size; (void)in_sizes; (void)n_in; (void)out_size;

  hipMemcpyAsync(bqkv, bq, 2048 * sizeof(float), hipMemcpyDeviceToDevice, stream);
  hipMemcpyAsync(bqkv + 2048, bk, 512 * sizeof(float), hipMemcpyDeviceToDevice, stream);
  hipMemcpyAsync(bqkv + 2560, bv, 512 * sizeof(float), hipMemcpyDeviceToDevice, stream);

  k_conv_bf16<<<4096, 256, 0, stream>>>(x, xb, 1048576);
  dim3 tb(32, 8);
  k_transpose_bf16<<<dim3(64, 64), tb, 0, stream>>>(Wq, wqkvT, 2048, 2048);
  k_transpose_bf16<<<dim3(16, 64), tb, 0, stream>>>(Wk, wqkvT + 2048 * 2048, 2048, 512);
  k_transpose_bf16<<<dim3(16, 64), tb, 0, stream>>>(Wv, wqkvT + 2560 * 2048, 2048, 512);
  k_transpose_bf16<<<dim3(64, 64), tb, 0, stream>>>(Wo, woT, 2048, 2048);

  k_gemm_bt<true><<<192, 512, 0, stream>>>(xb, wqkvT, bqkv, cqkv, 4096, 3072, 2048, 12, 192);
  k_transpose_v<<<dim3(64, 2, 16), tb, 0, stream>>>(cqkv, vtb);
  k_attn<<<dim3(8, 32, 2), 256, 0, stream>>>(cqkv, vtb, aout);
  k_gemm_bt<false><<<128, 512, 0, stream>>>(aout, woT, bo, out, 4096, 2048, 2048, 8, 128);
}